// Round 9
// baseline (648.768 us; speedup 1.0000x reference)
//
#include <hip/hip_runtime.h>
#include <hip/hip_bf16.h>

#define NNODES 30000
#define NEDGES 480000
#define HC 256
#define NEG_SLOPE 0.2f
#define NPART 8
#define EPP 60000                 // NEDGES / NPART
#define PN (NPART * NNODES)       // 240000
#define SCAN_CHUNK 1024
#define NCHUNK2 235               // ceil(PN / 1024)
#define NCHUNKM 30                // ceil(NNODES / 1024)
#define CPP 235                   // ceil(EPP / 256)
#define NFE 7680000               // NNODES * HC

typedef _Float16 half8 __attribute__((ext_vector_type(8)));
typedef _Float16 h4v __attribute__((ext_vector_type(4)));
typedef _Float16 h2 __attribute__((ext_vector_type(2)));
typedef float floatx4 __attribute__((ext_vector_type(4)));

// ---------------- prep: weight transpose+cvt (blocks 0..511) | edge histogram (rest) ----------------

__global__ void prep_kernel(const float* __restrict__ Wl, const float* __restrict__ Wr,
                            _Float16* __restrict__ WtL, _Float16* __restrict__ WtR,
                            const int* __restrict__ ei, int* __restrict__ deg_dst,
                            int* __restrict__ deg_src) {
    __shared__ float sh[32][33];
    int b = blockIdx.x;
    if (b < 512) {
        int e = b >> 6;
        int r0 = ((b >> 3) & 7) * 32, c0 = (b & 7) * 32;
        const float* W = (e < 4) ? Wl + (size_t)e * 65536 : Wr + (size_t)(e - 4) * 65536;
        _Float16* Wt = (e < 4) ? WtL + (size_t)e * 65536 : WtR + (size_t)(e - 4) * 65536;
        int x = threadIdx.x & 31, y = threadIdx.x >> 5;  // 32 x 8
#pragma unroll
        for (int j = 0; j < 4; j++) {
            int r = y + j * 8;
            sh[r][x] = W[(size_t)(r0 + r) * 256 + c0 + x];
        }
        __syncthreads();
#pragma unroll
        for (int j = 0; j < 4; j++) {
            int nn = y + j * 8;
            Wt[(size_t)(c0 + nn) * 256 + r0 + x] = (_Float16)sh[x][nn];
        }
    } else {
        b -= 512;
        int p = b & 7, c = b >> 3;
        int idx = c * 256 + threadIdx.x;
        if (idx >= EPP) return;
        int e = p * EPP + idx;
        int s = ei[e];
        int d = ei[NEDGES + e];
        atomicAdd(&deg_dst[p * NNODES + d], 1);
        atomicAdd(&deg_src[p * NNODES + s], 1);
    }
}

// ---------------- scans ----------------
// jobs: y=0 deg_dst->cur_dst (PN, exclusive), y=1 deg_src->cur_src,
//       y=2 sum_p(deg_dst)->mrp_dst[1..] (N, inclusive), y=3 same for src

__global__ void scanA_kernel(const int* __restrict__ deg_dst, const int* __restrict__ deg_src,
                             int* __restrict__ cur_dst, int* __restrict__ cur_src,
                             int* __restrict__ mrp_dst, int* __restrict__ mrp_src,
                             int* __restrict__ bsum) {
    __shared__ int sh[SCAN_CHUNK];
    const int y = blockIdx.y;
    const int nelem = (y < 2) ? PN : NNODES;
    if (blockIdx.x * SCAN_CHUNK >= nelem) return;
    int t = threadIdx.x;
    int gid = blockIdx.x * SCAN_CHUNK + t;
    int v = 0;
    if (gid < nelem) {
        if (y == 0) v = deg_dst[gid];
        else if (y == 1) v = deg_src[gid];
        else {
            const int* deg = (y == 2) ? deg_dst : deg_src;
#pragma unroll
            for (int p = 0; p < NPART; p++) v += deg[p * NNODES + gid];
        }
    }
    sh[t] = v;
    __syncthreads();
    for (int off = 1; off < SCAN_CHUNK; off <<= 1) {
        int u = (t >= off) ? sh[t - off] : 0;
        __syncthreads();
        sh[t] += u;
        __syncthreads();
    }
    if (gid < nelem) {
        if (y < 2) {
            ((y == 0) ? cur_dst : cur_src)[gid] = sh[t] - v;
        } else {
            ((y == 2) ? mrp_dst : mrp_src)[gid + 1] = sh[t];
        }
    }
    if (t == SCAN_CHUNK - 1) bsum[y * 256 + blockIdx.x] = sh[t];
}

__global__ void scan2_kernel(int* __restrict__ bsum) {
    int t = threadIdx.x;
    if (t < 4) {
        int cnt = (t < 2) ? NCHUNK2 : NCHUNKM;
        int run = 0;
        for (int i = 0; i < cnt; i++) {
            int v = bsum[t * 256 + i];
            bsum[t * 256 + i] = run;
            run += v;
        }
    }
}

__global__ void scanB_kernel(int* __restrict__ cur_dst, int* __restrict__ cur_src,
                             int* __restrict__ mrp_dst, int* __restrict__ mrp_src,
                             const int* __restrict__ bsum) {
    const int y = blockIdx.y;
    const int nelem = (y < 2) ? PN : NNODES;
    if (blockIdx.x * SCAN_CHUNK >= nelem) return;
    int t = threadIdx.x;
    int gid = blockIdx.x * SCAN_CHUNK + t;
    int base = bsum[y * 256 + blockIdx.x];
    if (gid < nelem) {
        if (y < 2) {
            ((y == 0) ? cur_dst : cur_src)[gid] += base;
        } else {
            ((y == 2) ? mrp_dst : mrp_src)[gid + 1] += base;
        }
    }
    if (gid == 0 && y >= 2) ((y == 2) ? mrp_dst : mrp_src)[0] = 0;
}

__global__ void fill_kernel(const int* __restrict__ ei, int* __restrict__ cur_dst,
                            int* __restrict__ cur_src, unsigned short* __restrict__ col_dst,
                            unsigned short* __restrict__ col_src) {
    int p = blockIdx.x & 7, c = blockIdx.x >> 3;
    int idx = c * 256 + threadIdx.x;
    if (idx >= EPP) return;
    int e = p * EPP + idx;
    int s = ei[e];
    int d = ei[NEDGES + e];
    int p0 = atomicAdd(&cur_dst[p * NNODES + d], 1);
    col_dst[p0] = (unsigned short)s;
    int p1 = atomicAdd(&cur_src[p * NNODES + s], 1);
    col_src[p1] = (unsigned short)d;
}

// merge 8 part-segments of each node into node-contiguous mcol (after fill: cur = segment ends)
__global__ void merge_kernel(const int* __restrict__ deg_dst, const int* __restrict__ deg_src,
                             const int* __restrict__ cur_dst, const int* __restrict__ cur_src,
                             const int* __restrict__ mrp_dst, const int* __restrict__ mrp_src,
                             const unsigned short* __restrict__ col_dst,
                             const unsigned short* __restrict__ col_src,
                             unsigned short* __restrict__ mcol_dst,
                             unsigned short* __restrict__ mcol_src) {
    const int z = blockIdx.y;
    const int* deg = z ? deg_src : deg_dst;
    const int* cur = z ? cur_src : cur_dst;
    const int* mrp = z ? mrp_src : mrp_dst;
    const unsigned short* col = z ? col_src : col_dst;
    unsigned short* mcol = z ? mcol_src : mcol_dst;
    int n = blockIdx.x * blockDim.x + threadIdx.x;
    if (n >= NNODES) return;
    int w = mrp[n];
#pragma unroll
    for (int p = 0; p < NPART; p++) {
        int e = cur[p * NNODES + n];
        int d = deg[p * NNODES + n];
        for (int k = e - d; k < e; k++) mcol[w++] = col[k];
    }
}

// ---------------- fp16 MFMA GEMM (round-6 structure: BK=32, reg-prefetch, LDS epilogue) ----------------
// 4 GEMMs fused via grid.y:
// y=0: hl_a = xs@Wl[e0];  y=1: hr_a = xt@Wr[e0]
// y=2: hl_b = xt@Wl[e1];  y=3: hr_b = xs@Wr[e1]

__device__ inline half8 ldA8(const _Float16* p) { return *(const half8*)p; }
__device__ inline half8 ldA8(const float* p) {
    float4 a = *(const float4*)p;
    float4 b = *(const float4*)(p + 4);
    half8 r = {(_Float16)a.x, (_Float16)a.y, (_Float16)a.z, (_Float16)a.w,
               (_Float16)b.x, (_Float16)b.y, (_Float16)b.z, (_Float16)b.w};
    return r;
}

#define EPI_STRIDE 264  // halfs

template <typename AT>
__global__ void __launch_bounds__(256)
gemm_f16(const AT* __restrict__ xs, const AT* __restrict__ xt,
         const _Float16* __restrict__ WtL, const _Float16* __restrict__ WtR,
         const float* __restrict__ bl, const float* __restrict__ br,
         _Float16* __restrict__ hbase, int e0) {
    const int y = blockIdx.y;
    const int e = e0 + (y >> 1);
    const AT* A = (y == 0 || y == 3) ? xs : xt;
    const bool left = (y & 1) == 0;
    const _Float16* Wt = (left ? WtL : WtR) + (size_t)e * 65536;
    const float* bvec = (left ? bl : br) + (size_t)e * HC;
    _Float16* C = hbase + (size_t)y * NFE;

    __shared__ __align__(16) _Float16 sh[10240];  // As(2048) | Bs(8192); reused by epilogue
    _Float16* As = sh;
    _Float16* Bs = sh + 2048;

    const int t = threadIdx.x;
    const int lane = t & 63, w = t >> 6;
    const int m0 = blockIdx.x * 64;
    const int rl = lane & 15, ch = lane >> 4;
    const int ar = t >> 2, ac = t & 3;

    floatx4 acc[4][4] = {};

    // prologue: load K-tile 0 into registers
    half8 av = {};
    {
        int gr = m0 + ar;
        if (gr < NNODES) av = ldA8(A + (size_t)gr * 256 + ac * 8);
    }
    half8 bv[4];
#pragma unroll
    for (int j = 0; j < 4; j++)
        bv[j] = *(const half8*)(Wt + (size_t)(ar + j * 64) * 256 + ac * 8);

    for (int k0 = 0; k0 < 256; k0 += 32) {
        __syncthreads();  // previous iteration's readers done
        *(half8*)(As + ar * 32 + (ac ^ ((ar >> 1) & 3)) * 8) = av;
#pragma unroll
        for (int j = 0; j < 4; j++) {
            int n = ar + j * 64;
            *(half8*)(Bs + n * 32 + (ac ^ ((n >> 1) & 3)) * 8) = bv[j];
        }
        __syncthreads();

        // prefetch next K-tile (latency hides under ds_read + MFMA below)
        if (k0 + 32 < 256) {
            int gr = m0 + ar;
            if (gr < NNODES) av = ldA8(A + (size_t)gr * 256 + (k0 + 32) + ac * 8);
#pragma unroll
            for (int j = 0; j < 4; j++)
                bv[j] = *(const half8*)(Wt + (size_t)(ar + j * 64) * 256 + (k0 + 32) + ac * 8);
        }

        half8 a[4], b[4];
#pragma unroll
        for (int fm = 0; fm < 4; fm++) {
            int r = fm * 16 + rl;
            a[fm] = *(const half8*)(As + r * 32 + (ch ^ ((r >> 1) & 3)) * 8);
        }
#pragma unroll
        for (int fn = 0; fn < 4; fn++) {
            int n = w * 64 + fn * 16 + rl;
            b[fn] = *(const half8*)(Bs + n * 32 + (ch ^ ((n >> 1) & 3)) * 8);
        }
#pragma unroll
        for (int fm = 0; fm < 4; fm++)
#pragma unroll
            for (int fn = 0; fn < 4; fn++)
                acc[fm][fn] = __builtin_amdgcn_mfma_f32_16x16x32_f16(a[fm], b[fn], acc[fm][fn], 0, 0, 0);
    }

    // epilogue: stage through LDS, store 64B-contiguous per thread
    float bb[4];
#pragma unroll
    for (int fn = 0; fn < 4; fn++) bb[fn] = bvec[w * 64 + fn * 16 + rl];

#pragma unroll
    for (int hh = 0; hh < 2; hh++) {
        __syncthreads();
#pragma unroll
        for (int f2 = 0; f2 < 2; f2++) {
            int fm = hh * 2 + f2;
#pragma unroll
            for (int fn = 0; fn < 4; fn++) {
                int colb = w * 64 + fn * 16 + rl;
#pragma unroll
                for (int j = 0; j < 4; j++) {
                    int lr = f2 * 16 + ch * 4 + j;  // 0..31
                    sh[lr * EPI_STRIDE + colb] = (_Float16)(acc[fm][fn][j] + bb[fn]);
                }
            }
        }
        __syncthreads();
        int lr = t >> 3;            // 0..31
        int cseg = (t & 7) * 32;    // 8 segments x 32 cols (64B)
        int gr = m0 + hh * 32 + lr;
        if (gr < NNODES) {
#pragma unroll
            for (int q = 0; q < 4; q++)
                *(half8*)(C + (size_t)gr * 256 + cseg + q * 8) =
                    *(const half8*)(sh + lr * EPI_STRIDE + cseg + q * 8);
        }
    }
}

// ---------------- fused attention + aggregate (head-sliced, XCD-affine) ----------------
// One block = 4 nodes x 1 head (32 channels). bid.x = nb*8 + head, so head -> XCD
// via the %8 round-robin dispatch; each XCD's gather table is its head slice
// (30000*32*2B = 1.92MB, L2-resident). Per wave: 8 edges x 8 lanes x 4ch.

__device__ inline void stslice(float* p, float o0, float o1, float o2, float o3) {
    floatx4 v = {o0, o1, o2, o3};
    *(floatx4*)p = v;
}
__device__ inline void stslice(_Float16* p, float o0, float o1, float o2, float o3) {
    h4v h = {(_Float16)o0, (_Float16)o1, (_Float16)o2, (_Float16)o3};
    *(h4v*)p = h;
}

template <typename OT>
__global__ void __launch_bounds__(256)
agg_kernel(const _Float16* __restrict__ hbase,
           const int* __restrict__ mrp_dst, const unsigned short* __restrict__ mcol_dst,
           const int* __restrict__ mrp_src, const unsigned short* __restrict__ mcol_src,
           const float* __restrict__ att, const float* __restrict__ bias,
           OT* __restrict__ out0, OT* __restrict__ out1, int e0, int do_relu) {
    const int z = blockIdx.y;
    const _Float16* hl = hbase + (size_t)z * 2 * NFE;
    const _Float16* hr = hl + NFE;
    const int* mrp = z ? mrp_src : mrp_dst;
    const unsigned short* mcol = z ? mcol_src : mcol_dst;
    const float* attz = att + (size_t)(e0 + z) * HC;
    const float* biasz = bias + (size_t)(e0 + z) * HC;
    OT* out = z ? out1 : out0;

    const int wave = threadIdx.x >> 6;
    const int lane = threadIdx.x & 63;
    const int head = blockIdx.x & 7;
    const int n = (blockIdx.x >> 3) * 4 + wave;
    if (n >= NNODES) return;
    const int g = lane >> 3;                  // edge slot 0..7
    const int cl = lane & 7;                  // channel quad 0..7
    const int c = (head << 5) + (cl << 2);    // global channel base

    const _Float16* hlc = hl + c;
    h4v hrv = *(const h4v*)(hr + (size_t)n * HC + c);
    float4 a4 = *(const float4*)(attz + c);
    const h2 at0 = {(_Float16)a4.x, (_Float16)a4.y};
    const h2 at1 = {(_Float16)a4.z, (_Float16)a4.w};
    const h2 negv = {(_Float16)NEG_SLOPE, (_Float16)NEG_SLOPE};
    const h2 hr0 = {hrv[0], hrv[1]};
    const h2 hr1 = {hrv[2], hrv[3]};

    float acc0 = 0.f, acc1 = 0.f, acc2 = 0.f, acc3 = 0.f, denom = 0.f;
    int beg = mrp[n], end = mrp[n + 1];

    for (int i = beg; i < end; i += 8) {
        int eid = i + g;
        bool valid = eid < end;
        int s = (int)mcol[valid ? eid : i];
        h4v hv = *(const h4v*)(hlc + ((size_t)s << 8));
        h2 x0 = h2{hv[0], hv[1]} + hr0;
        h2 x1 = h2{hv[2], hv[3]} + hr1;
        h2 l0 = __builtin_elementwise_max(x0, x0 * negv);
        h2 l1 = __builtin_elementwise_max(x1, x1 * negv);
        float v = __builtin_amdgcn_fdot2(l0, at0, 0.f, false);
        v = __builtin_amdgcn_fdot2(l1, at1, v, false);
        v += __shfl_xor(v, 1);
        v += __shfl_xor(v, 2);
        v += __shfl_xor(v, 4);
        float pe = __expf(v);
        if (!valid) pe = 0.f;
        denom += pe;
        acc0 = fmaf((float)hv[0], pe, acc0);
        acc1 = fmaf((float)hv[1], pe, acc1);
        acc2 = fmaf((float)hv[2], pe, acc2);
        acc3 = fmaf((float)hv[3], pe, acc3);
    }

    // merge the 8 edge-slot partials
#pragma unroll
    for (int off = 8; off < 64; off <<= 1) {
        denom += __shfl_xor(denom, off);
        acc0 += __shfl_xor(acc0, off);
        acc1 += __shfl_xor(acc1, off);
        acc2 += __shfl_xor(acc2, off);
        acc3 += __shfl_xor(acc3, off);
    }

    if (lane < 8) {
        float inv = 1.f / (denom + 1e-16f);
        float4 b4 = *(const float4*)(biasz + c);
        float o0 = acc0 * inv + b4.x;
        float o1 = acc1 * inv + b4.y;
        float o2 = acc2 * inv + b4.z;
        float o3 = acc3 * inv + b4.w;
        if (do_relu) {
            o0 = fmaxf(o0, 0.f);
            o1 = fmaxf(o1, 0.f);
            o2 = fmaxf(o2, 0.f);
            o3 = fmaxf(o3, 0.f);
        }
        stslice(out + (size_t)n * HC + c, o0, o1, o2, o3);
    }
}

// ---------------- launch ----------------

extern "C" void kernel_launch(void* const* d_in, const int* in_sizes, int n_in,
                              void* d_out, int out_size, void* d_ws, size_t ws_size,
                              hipStream_t stream) {
    const float* s = (const float*)d_in[0];
    const float* t = (const float*)d_in[1];
    const float* Wl = (const float*)d_in[2];
    const float* bl = (const float*)d_in[3];
    const float* Wr = (const float*)d_in[4];
    const float* br = (const float*)d_in[5];
    const float* att = (const float*)d_in[6];
    const float* bias = (const float*)d_in[7];
    const int* ei = (const int*)d_in[8];
    float* out = (float*)d_out;

    const size_t NF = (size_t)NFE;

    // workspace layout
    _Float16* os16 = (_Float16*)d_ws;         // NF
    _Float16* ot16 = os16 + NF;               // NF
    _Float16* hbase = ot16 + NF;              // 4*NF
    _Float16* WtL = hbase + 4 * NF;           // 4*65536
    _Float16* WtR = WtL + 4 * 65536;          // 4*65536
    int* deg_dst = (int*)(WtR + 4 * 65536);   // PN
    int* deg_src = deg_dst + PN;              // PN
    int* cur_dst = deg_src + PN;              // PN
    int* cur_src = cur_dst + PN;              // PN
    int* mrp_dst = cur_src + PN;              // N+1
    int* mrp_src = mrp_dst + (NNODES + 1);    // N+1
    int* bsum = mrp_src + (NNODES + 1);       // 1024
    unsigned short* col_dst = (unsigned short*)(bsum + 1024);  // E
    unsigned short* col_src = col_dst + NEDGES;                // E
    unsigned short* mcol_dst = col_src + NEDGES;               // E
    unsigned short* mcol_src = mcol_dst + NEDGES;              // E

    // ---- CSR build + weight prep ----
    hipMemsetAsync(deg_dst, 0, 2 * PN * sizeof(int), stream);
    prep_kernel<<<512 + NPART * CPP, 256, 0, stream>>>(Wl, Wr, WtL, WtR, ei, deg_dst, deg_src);
    {
        dim3 g(NCHUNK2, 4);
        scanA_kernel<<<g, SCAN_CHUNK, 0, stream>>>(deg_dst, deg_src, cur_dst, cur_src,
                                                   mrp_dst, mrp_src, bsum);
        scan2_kernel<<<1, 64, 0, stream>>>(bsum);
        scanB_kernel<<<g, SCAN_CHUNK, 0, stream>>>(cur_dst, cur_src, mrp_dst, mrp_src, bsum);
    }
    fill_kernel<<<NPART * CPP, 256, 0, stream>>>(ei, cur_dst, cur_src, col_dst, col_src);
    merge_kernel<<<dim3(118, 2), 256, 0, stream>>>(deg_dst, deg_src, cur_dst, cur_src,
                                                   mrp_dst, mrp_src, col_dst, col_src,
                                                   mcol_dst, mcol_src);

    dim3 ggemm((NNODES + 63) / 64, 4);
    dim3 gagg(((NNODES + 3) / 4) * 8, 2);

    // layer 0 (fp32 inputs, relu)
    gemm_f16<float><<<ggemm, 256, 0, stream>>>(s, t, WtL, WtR, bl, br, hbase, 0);
    agg_kernel<_Float16><<<gagg, 256, 0, stream>>>(hbase, mrp_dst, mcol_dst, mrp_src, mcol_src,
                                                   att, bias, os16, ot16, 0, 1);
    // layer 1 (fp16 inputs, identity, fp32 out)
    gemm_f16<_Float16><<<ggemm, 256, 0, stream>>>(os16, ot16, WtL, WtR, bl, br, hbase, 2);
    agg_kernel<float><<<gagg, 256, 0, stream>>>(hbase, mrp_dst, mcol_dst, mrp_src, mcol_src,
                                                att, bias, out, out + NF, 2, 0);
}

// Round 10
// 587.207 us; speedup vs baseline: 1.1048x; 1.1048x over previous
//
#include <hip/hip_runtime.h>
#include <hip/hip_bf16.h>

#define NNODES 30000
#define NEDGES 480000
#define HC 256
#define NEG_SLOPE 0.2f
#define NPART 8
#define EPP 60000                 // NEDGES / NPART
#define PN (NPART * NNODES)       // 240000
#define SCAN_CHUNK 1024
#define NCHUNK2 235               // ceil(PN / 1024)
#define NCHUNKM 30                // ceil(NNODES / 1024)
#define CPP 235                   // ceil(EPP / 256)
#define NFE 7680000               // NNODES * HC

typedef _Float16 half8 __attribute__((ext_vector_type(8)));
typedef _Float16 h4v __attribute__((ext_vector_type(4)));
typedef _Float16 h2 __attribute__((ext_vector_type(2)));
typedef float floatx4 __attribute__((ext_vector_type(4)));

// ---------------- prep: weight transpose+cvt (blocks 0..511) | edge histogram (rest) ----------------

__global__ void prep_kernel(const float* __restrict__ Wl, const float* __restrict__ Wr,
                            _Float16* __restrict__ WtL, _Float16* __restrict__ WtR,
                            const int* __restrict__ ei, int* __restrict__ deg_dst,
                            int* __restrict__ deg_src) {
    __shared__ float sh[32][33];
    int b = blockIdx.x;
    if (b < 512) {
        int e = b >> 6;
        int r0 = ((b >> 3) & 7) * 32, c0 = (b & 7) * 32;
        const float* W = (e < 4) ? Wl + (size_t)e * 65536 : Wr + (size_t)(e - 4) * 65536;
        _Float16* Wt = (e < 4) ? WtL + (size_t)e * 65536 : WtR + (size_t)(e - 4) * 65536;
        int x = threadIdx.x & 31, y = threadIdx.x >> 5;  // 32 x 8
#pragma unroll
        for (int j = 0; j < 4; j++) {
            int r = y + j * 8;
            sh[r][x] = W[(size_t)(r0 + r) * 256 + c0 + x];
        }
        __syncthreads();
#pragma unroll
        for (int j = 0; j < 4; j++) {
            int nn = y + j * 8;
            Wt[(size_t)(c0 + nn) * 256 + r0 + x] = (_Float16)sh[x][nn];
        }
    } else {
        b -= 512;
        int p = b & 7, c = b >> 3;
        int idx = c * 256 + threadIdx.x;
        if (idx >= EPP) return;
        int e = p * EPP + idx;
        int s = ei[e];
        int d = ei[NEDGES + e];
        atomicAdd(&deg_dst[p * NNODES + d], 1);
        atomicAdd(&deg_src[p * NNODES + s], 1);
    }
}

// ---------------- single fused scan (local scans + last-block base scan) ----------------
// y=0: deg_dst -> cur_dst (local exclusive); y=1: deg_src -> cur_src
// y=2: sum_p deg_dst -> mrpl_dst[gid+1] (local inclusive); y=3: same for src
// bsum rows 0..3 get chunk totals; the LAST block converts them to exclusive bases.

__global__ void scanA_kernel(const int* __restrict__ deg_dst, const int* __restrict__ deg_src,
                             int* __restrict__ cur_dst, int* __restrict__ cur_src,
                             int* __restrict__ mrpl_dst, int* __restrict__ mrpl_src,
                             int* __restrict__ bsum, int* __restrict__ done) {
    __shared__ int sh[SCAN_CHUNK];
    __shared__ int islast;
    const int y = blockIdx.y;
    const int nelem = (y < 2) ? PN : NNODES;
    const bool active = (blockIdx.x * SCAN_CHUNK < nelem);
    int t = threadIdx.x;
    if (active) {
        int gid = blockIdx.x * SCAN_CHUNK + t;
        int v = 0;
        if (gid < nelem) {
            if (y == 0) v = deg_dst[gid];
            else if (y == 1) v = deg_src[gid];
            else {
                const int* deg = (y == 2) ? deg_dst : deg_src;
#pragma unroll
                for (int p = 0; p < NPART; p++) v += deg[p * NNODES + gid];
            }
        }
        sh[t] = v;
        __syncthreads();
        for (int off = 1; off < SCAN_CHUNK; off <<= 1) {
            int u = (t >= off) ? sh[t - off] : 0;
            __syncthreads();
            sh[t] += u;
            __syncthreads();
        }
        if (gid < nelem) {
            if (y < 2) ((y == 0) ? cur_dst : cur_src)[gid] = sh[t] - v;
            else ((y == 2) ? mrpl_dst : mrpl_src)[gid + 1] = sh[t];
        }
        if (t == SCAN_CHUNK - 1) bsum[y * 256 + blockIdx.x] = sh[t];
    }
    // ticket: last block to arrive converts bsum totals -> exclusive bases
    __threadfence();
    if (t == 0) {
        int v = atomicAdd(done, 1);
        islast = (v == NCHUNK2 * 4 - 1) ? 1 : 0;
    }
    __syncthreads();
    if (islast) {
        __threadfence();
        if (t < 4) {
            int cnt = (t < 2) ? NCHUNK2 : NCHUNKM;
            int run = 0;
            for (int i = 0; i < cnt; i++) {
                int v = bsum[t * 256 + i];
                bsum[t * 256 + i] = run;
                run += v;
            }
        }
    }
}

// ---------------- fill (adds chunk base from bsum inline) ----------------

__global__ void fill_kernel(const int* __restrict__ ei, int* __restrict__ cur_dst,
                            int* __restrict__ cur_src, const int* __restrict__ bsum,
                            unsigned short* __restrict__ col_dst,
                            unsigned short* __restrict__ col_src) {
    int p = blockIdx.x & 7, c = blockIdx.x >> 3;
    int idx = c * 256 + threadIdx.x;
    if (idx >= EPP) return;
    int e = p * EPP + idx;
    int s = ei[e];
    int d = ei[NEDGES + e];
    int i0 = p * NNODES + d;
    int p0 = atomicAdd(&cur_dst[i0], 1) + bsum[i0 >> 10];
    col_dst[p0] = (unsigned short)s;
    int i1 = p * NNODES + s;
    int p1 = atomicAdd(&cur_src[i1], 1) + bsum[256 + (i1 >> 10)];
    col_src[p1] = (unsigned short)d;
}

// ---------------- merge (also finalizes mrp) ----------------
// after fill: cur[i] = local inclusive end; global end = cur[i] + bsum[z*256 + i>>10]
// node start = mrpl[n+1] + bsum[(2+z)*256 + n>>10] - mdeg(n)

__global__ void merge_kernel(const int* __restrict__ deg_dst, const int* __restrict__ deg_src,
                             const int* __restrict__ cur_dst, const int* __restrict__ cur_src,
                             const int* __restrict__ mrpl_dst, const int* __restrict__ mrpl_src,
                             int* __restrict__ mrpf_dst, int* __restrict__ mrpf_src,
                             const int* __restrict__ bsum,
                             const unsigned short* __restrict__ col_dst,
                             const unsigned short* __restrict__ col_src,
                             unsigned short* __restrict__ mcol_dst,
                             unsigned short* __restrict__ mcol_src) {
    const int z = blockIdx.y;
    const int* deg = z ? deg_src : deg_dst;
    const int* cur = z ? cur_src : cur_dst;
    const int* mrpl = z ? mrpl_src : mrpl_dst;
    int* mrpf = z ? mrpf_src : mrpf_dst;
    const unsigned short* col = z ? col_src : col_dst;
    unsigned short* mcol = z ? mcol_src : mcol_dst;
    int n = blockIdx.x * blockDim.x + threadIdx.x;
    if (n >= NNODES) return;
    int dv[NPART];
    int mdeg = 0;
#pragma unroll
    for (int p = 0; p < NPART; p++) {
        dv[p] = deg[p * NNODES + n];
        mdeg += dv[p];
    }
    int start = mrpl[n + 1] + bsum[(2 + z) * 256 + (n >> 10)] - mdeg;
    mrpf[n] = start;
    if (n == NNODES - 1) mrpf[NNODES] = NEDGES;
    int w = start;
#pragma unroll
    for (int p = 0; p < NPART; p++) {
        int i = p * NNODES + n;
        int egl = cur[i] + bsum[z * 256 + (i >> 10)];
        for (int k = egl - dv[p]; k < egl; k++) mcol[w++] = col[k];
    }
}

// ---------------- fp16 MFMA GEMM (BK=32, reg-prefetch, LDS epilogue) ----------------
// y=0: hl_a = xs@Wl[e0];  y=1: hr_a = xt@Wr[e0]
// y=2: hl_b = xt@Wl[e1];  y=3: hr_b = xs@Wr[e1]

__device__ inline half8 ldA8(const _Float16* p) { return *(const half8*)p; }
__device__ inline half8 ldA8(const float* p) {
    float4 a = *(const float4*)p;
    float4 b = *(const float4*)(p + 4);
    half8 r = {(_Float16)a.x, (_Float16)a.y, (_Float16)a.z, (_Float16)a.w,
               (_Float16)b.x, (_Float16)b.y, (_Float16)b.z, (_Float16)b.w};
    return r;
}

#define EPI_STRIDE 264  // halfs

template <typename AT>
__global__ void __launch_bounds__(256)
gemm_f16(const AT* __restrict__ xs, const AT* __restrict__ xt,
         const _Float16* __restrict__ WtL, const _Float16* __restrict__ WtR,
         const float* __restrict__ bl, const float* __restrict__ br,
         _Float16* __restrict__ hbase, int e0) {
    const int y = blockIdx.y;
    const int e = e0 + (y >> 1);
    const AT* A = (y == 0 || y == 3) ? xs : xt;
    const bool left = (y & 1) == 0;
    const _Float16* Wt = (left ? WtL : WtR) + (size_t)e * 65536;
    const float* bvec = (left ? bl : br) + (size_t)e * HC;
    _Float16* C = hbase + (size_t)y * NFE;

    __shared__ __align__(16) _Float16 sh[10240];  // As(2048) | Bs(8192); reused by epilogue
    _Float16* As = sh;
    _Float16* Bs = sh + 2048;

    const int t = threadIdx.x;
    const int lane = t & 63, w = t >> 6;
    const int m0 = blockIdx.x * 64;
    const int rl = lane & 15, ch = lane >> 4;
    const int ar = t >> 2, ac = t & 3;

    floatx4 acc[4][4] = {};

    half8 av = {};
    {
        int gr = m0 + ar;
        if (gr < NNODES) av = ldA8(A + (size_t)gr * 256 + ac * 8);
    }
    half8 bv[4];
#pragma unroll
    for (int j = 0; j < 4; j++)
        bv[j] = *(const half8*)(Wt + (size_t)(ar + j * 64) * 256 + ac * 8);

    for (int k0 = 0; k0 < 256; k0 += 32) {
        __syncthreads();
        *(half8*)(As + ar * 32 + (ac ^ ((ar >> 1) & 3)) * 8) = av;
#pragma unroll
        for (int j = 0; j < 4; j++) {
            int n = ar + j * 64;
            *(half8*)(Bs + n * 32 + (ac ^ ((n >> 1) & 3)) * 8) = bv[j];
        }
        __syncthreads();

        if (k0 + 32 < 256) {
            int gr = m0 + ar;
            if (gr < NNODES) av = ldA8(A + (size_t)gr * 256 + (k0 + 32) + ac * 8);
#pragma unroll
            for (int j = 0; j < 4; j++)
                bv[j] = *(const half8*)(Wt + (size_t)(ar + j * 64) * 256 + (k0 + 32) + ac * 8);
        }

        half8 a[4], b[4];
#pragma unroll
        for (int fm = 0; fm < 4; fm++) {
            int r = fm * 16 + rl;
            a[fm] = *(const half8*)(As + r * 32 + (ch ^ ((r >> 1) & 3)) * 8);
        }
#pragma unroll
        for (int fn = 0; fn < 4; fn++) {
            int n = w * 64 + fn * 16 + rl;
            b[fn] = *(const half8*)(Bs + n * 32 + (ch ^ ((n >> 1) & 3)) * 8);
        }
#pragma unroll
        for (int fm = 0; fm < 4; fm++)
#pragma unroll
            for (int fn = 0; fn < 4; fn++)
                acc[fm][fn] = __builtin_amdgcn_mfma_f32_16x16x32_f16(a[fm], b[fn], acc[fm][fn], 0, 0, 0);
    }

    float bb[4];
#pragma unroll
    for (int fn = 0; fn < 4; fn++) bb[fn] = bvec[w * 64 + fn * 16 + rl];

#pragma unroll
    for (int hh = 0; hh < 2; hh++) {
        __syncthreads();
#pragma unroll
        for (int f2 = 0; f2 < 2; f2++) {
            int fm = hh * 2 + f2;
#pragma unroll
            for (int fn = 0; fn < 4; fn++) {
                int colb = w * 64 + fn * 16 + rl;
#pragma unroll
                for (int j = 0; j < 4; j++) {
                    int lr = f2 * 16 + ch * 4 + j;  // 0..31
                    sh[lr * EPI_STRIDE + colb] = (_Float16)(acc[fm][fn][j] + bb[fn]);
                }
            }
        }
        __syncthreads();
        int lr = t >> 3;            // 0..31
        int cseg = (t & 7) * 32;    // 8 segments x 32 cols (64B)
        int gr = m0 + hh * 32 + lr;
        if (gr < NNODES) {
#pragma unroll
            for (int q = 0; q < 4; q++)
                *(half8*)(C + (size_t)gr * 256 + cseg + q * 8) =
                    *(const half8*)(sh + lr * EPI_STRIDE + cseg + q * 8);
        }
    }
}

// ---------------- fused attention + aggregate (2 edges/wave, 8ch/lane) ----------------

__device__ __forceinline__ void edge_body(half8 hv, half8 hrv, const h2* att2,
                                          float* acc, float& denom, bool valid) {
    const h2 negv = {(_Float16)NEG_SLOPE, (_Float16)NEG_SLOPE};
    const h2* hvp = (const h2*)&hv;
    const h2* hrp = (const h2*)&hrv;
    float v = 0.f;
#pragma unroll
    for (int k = 0; k < 4; k++) {
        h2 x = hvp[k] + hrp[k];
        h2 lk = __builtin_elementwise_max(x, x * negv);
        v = __builtin_amdgcn_fdot2(lk, att2[k], v, false);
    }
    v += __shfl_xor(v, 1);
    v += __shfl_xor(v, 2);
    float pe = __expf(v);
    if (!valid) pe = 0.f;
    denom += pe;
#pragma unroll
    for (int k = 0; k < 8; k++) acc[k] = fmaf((float)hv[k], pe, acc[k]);
}

__device__ inline void store8(float* p, const float* o) {
    floatx4 v0 = {o[0], o[1], o[2], o[3]};
    floatx4 v1 = {o[4], o[5], o[6], o[7]};
    *(floatx4*)p = v0;
    *(floatx4*)(p + 4) = v1;
}
__device__ inline void store8(_Float16* p, const float* o) {
    half8 h = {(_Float16)o[0], (_Float16)o[1], (_Float16)o[2], (_Float16)o[3],
               (_Float16)o[4], (_Float16)o[5], (_Float16)o[6], (_Float16)o[7]};
    *(half8*)p = h;
}

template <typename OT>
__global__ void __launch_bounds__(256)
agg_kernel(const _Float16* __restrict__ hbase,
           const int* __restrict__ mrp_dst, const unsigned short* __restrict__ mcol_dst,
           const int* __restrict__ mrp_src, const unsigned short* __restrict__ mcol_src,
           const float* __restrict__ att, const float* __restrict__ bias,
           OT* __restrict__ out0, OT* __restrict__ out1, int e0, int do_relu) {
    const int z = blockIdx.y;
    const _Float16* hl = hbase + (size_t)z * 2 * NFE;
    const _Float16* hr = hl + NFE;
    const int* mrp = z ? mrp_src : mrp_dst;
    const unsigned short* mcol = z ? mcol_src : mcol_dst;
    const float* attz = att + (size_t)(e0 + z) * HC;
    const float* biasz = bias + (size_t)(e0 + z) * HC;
    OT* out = z ? out1 : out0;

    int wave = threadIdx.x >> 6;
    int lane = threadIdx.x & 63;
    int n = blockIdx.x * 4 + wave;
    if (n >= NNODES) return;
    int h = lane >> 5;       // edge parity within the wave
    int cl = lane & 31;      // channel block (8 channels)
    int c8 = cl << 3;

    const _Float16* hlc = hl + c8;
    half8 hrv = *(const half8*)(hr + (size_t)n * HC + c8);
    float attf[8];
    *(float4*)(attf) = *(const float4*)(attz + c8);
    *(float4*)(attf + 4) = *(const float4*)(attz + c8 + 4);
    h2 att2[4];
#pragma unroll
    for (int k = 0; k < 4; k++) att2[k] = h2{(_Float16)attf[2 * k], (_Float16)attf[2 * k + 1]};

    float acc[8] = {};
    float denom = 0.f;
    int beg = mrp[n], end = mrp[n + 1];

    int i = beg;
    for (; i + 4 <= end; i += 4) {
        int s0 = (int)mcol[i + h];
        int s1 = (int)mcol[i + 2 + h];
        half8 hv0 = *(const half8*)(hlc + ((size_t)s0 << 8));
        half8 hv1 = *(const half8*)(hlc + ((size_t)s1 << 8));
        edge_body(hv0, hrv, att2, acc, denom, true);
        edge_body(hv1, hrv, att2, acc, denom, true);
    }
    for (; i < end; i += 2) {
        int ei = i + h;
        bool valid = ei < end;
        int s0 = (int)mcol[valid ? ei : end - 1];
        half8 hv0 = *(const half8*)(hlc + ((size_t)s0 << 8));
        edge_body(hv0, hrv, att2, acc, denom, valid);
    }

    // merge the two half-wave partials
#pragma unroll
    for (int k = 0; k < 8; k++) acc[k] += __shfl_xor(acc[k], 32);
    denom += __shfl_xor(denom, 32);

    if (lane < 32) {
        float inv = 1.f / (denom + 1e-16f);
        float o[8];
        float b8[8];
        *(float4*)(b8) = *(const float4*)(biasz + c8);
        *(float4*)(b8 + 4) = *(const float4*)(biasz + c8 + 4);
#pragma unroll
        for (int k = 0; k < 8; k++) {
            o[k] = acc[k] * inv + b8[k];
            if (do_relu) o[k] = fmaxf(o[k], 0.f);
        }
        store8(out + (size_t)n * HC + c8, o);
    }
}

// ---------------- launch ----------------

extern "C" void kernel_launch(void* const* d_in, const int* in_sizes, int n_in,
                              void* d_out, int out_size, void* d_ws, size_t ws_size,
                              hipStream_t stream) {
    const float* s = (const float*)d_in[0];
    const float* t = (const float*)d_in[1];
    const float* Wl = (const float*)d_in[2];
    const float* bl = (const float*)d_in[3];
    const float* Wr = (const float*)d_in[4];
    const float* br = (const float*)d_in[5];
    const float* att = (const float*)d_in[6];
    const float* bias = (const float*)d_in[7];
    const int* ei = (const int*)d_in[8];
    float* out = (float*)d_out;

    const size_t NF = (size_t)NFE;

    // workspace layout
    _Float16* os16 = (_Float16*)d_ws;         // NF
    _Float16* ot16 = os16 + NF;               // NF
    _Float16* hbase = ot16 + NF;              // 4*NF
    _Float16* WtL = hbase + 4 * NF;           // 4*65536
    _Float16* WtR = WtL + 4 * 65536;          // 4*65536
    int* deg_dst = (int*)(WtR + 4 * 65536);   // PN
    int* deg_src = deg_dst + PN;              // PN
    int* done = deg_src + PN;                 // 4 (memset with deg)
    int* cur_dst = done + 4;                  // PN
    int* cur_src = cur_dst + PN;              // PN
    int* mrpl_dst = cur_src + PN;             // N+1
    int* mrpl_src = mrpl_dst + (NNODES + 1);  // N+1
    int* mrpf_dst = mrpl_src + (NNODES + 1);  // N+1
    int* mrpf_src = mrpf_dst + (NNODES + 1);  // N+1
    int* bsum = mrpf_src + (NNODES + 1);      // 1024
    unsigned short* col_dst = (unsigned short*)(bsum + 1024);  // E
    unsigned short* col_src = col_dst + NEDGES;                // E
    unsigned short* mcol_dst = col_src + NEDGES;               // E
    unsigned short* mcol_src = mcol_dst + NEDGES;              // E

    // ---- CSR build + weight prep ----
    hipMemsetAsync(deg_dst, 0, (2 * PN + 4) * sizeof(int), stream);
    prep_kernel<<<512 + NPART * CPP, 256, 0, stream>>>(Wl, Wr, WtL, WtR, ei, deg_dst, deg_src);
    scanA_kernel<<<dim3(NCHUNK2, 4), SCAN_CHUNK, 0, stream>>>(deg_dst, deg_src, cur_dst, cur_src,
                                                              mrpl_dst, mrpl_src, bsum, done);
    fill_kernel<<<NPART * CPP, 256, 0, stream>>>(ei, cur_dst, cur_src, bsum, col_dst, col_src);
    merge_kernel<<<dim3(118, 2), 256, 0, stream>>>(deg_dst, deg_src, cur_dst, cur_src,
                                                   mrpl_dst, mrpl_src, mrpf_dst, mrpf_src, bsum,
                                                   col_dst, col_src, mcol_dst, mcol_src);

    dim3 ggemm((NNODES + 63) / 64, 4);
    dim3 gagg((NNODES + 3) / 4, 2);

    // layer 0 (fp32 inputs, relu)
    gemm_f16<float><<<ggemm, 256, 0, stream>>>(s, t, WtL, WtR, bl, br, hbase, 0);
    agg_kernel<_Float16><<<gagg, 256, 0, stream>>>(hbase, mrpf_dst, mcol_dst, mrpf_src, mcol_src,
                                                   att, bias, os16, ot16, 0, 1);
    // layer 1 (fp16 inputs, identity, fp32 out)
    gemm_f16<_Float16><<<ggemm, 256, 0, stream>>>(os16, ot16, WtL, WtR, bl, br, hbase, 2);
    agg_kernel<float><<<gagg, 256, 0, stream>>>(hbase, mrpf_dst, mcol_dst, mrpf_src, mcol_src,
                                                att, bias, out, out + NF, 2, 0);
}

// Round 11
// 358.872 us; speedup vs baseline: 1.8078x; 1.6363x over previous
//
#include <hip/hip_runtime.h>
#include <hip/hip_bf16.h>

#define NNODES 30000
#define NEDGES 480000
#define HC 256
#define NEG_SLOPE 0.2f
#define NPART 8
#define EPP 60000                 // NEDGES / NPART
#define PN (NPART * NNODES)       // 240000
#define SCAN_CHUNK 1024
#define NCHUNK2 235               // ceil(PN / 1024)
#define NCHUNKM 30                // ceil(NNODES / 1024)
#define CPP 235                   // ceil(EPP / 256)
#define NFE 7680000               // NNODES * HC

typedef _Float16 half8 __attribute__((ext_vector_type(8)));
typedef _Float16 h4v __attribute__((ext_vector_type(4)));
typedef _Float16 h2 __attribute__((ext_vector_type(2)));
typedef float floatx4 __attribute__((ext_vector_type(4)));

// ---------------- prep: weight transpose+cvt (blocks 0..511) | edge histogram (rest) ----------------

__global__ void prep_kernel(const float* __restrict__ Wl, const float* __restrict__ Wr,
                            _Float16* __restrict__ WtL, _Float16* __restrict__ WtR,
                            const int* __restrict__ ei, int* __restrict__ deg_dst,
                            int* __restrict__ deg_src) {
    __shared__ float sh[32][33];
    int b = blockIdx.x;
    if (b < 512) {
        int e = b >> 6;
        int r0 = ((b >> 3) & 7) * 32, c0 = (b & 7) * 32;
        const float* W = (e < 4) ? Wl + (size_t)e * 65536 : Wr + (size_t)(e - 4) * 65536;
        _Float16* Wt = (e < 4) ? WtL + (size_t)e * 65536 : WtR + (size_t)(e - 4) * 65536;
        int x = threadIdx.x & 31, y = threadIdx.x >> 5;  // 32 x 8
#pragma unroll
        for (int j = 0; j < 4; j++) {
            int r = y + j * 8;
            sh[r][x] = W[(size_t)(r0 + r) * 256 + c0 + x];
        }
        __syncthreads();
#pragma unroll
        for (int j = 0; j < 4; j++) {
            int nn = y + j * 8;
            Wt[(size_t)(c0 + nn) * 256 + r0 + x] = (_Float16)sh[x][nn];
        }
    } else {
        b -= 512;
        int p = b & 7, c = b >> 3;
        int idx = c * 256 + threadIdx.x;
        if (idx >= EPP) return;
        int e = p * EPP + idx;
        int s = ei[e];
        int d = ei[NEDGES + e];
        atomicAdd(&deg_dst[p * NNODES + d], 1);
        atomicAdd(&deg_src[p * NNODES + s], 1);
    }
}

// ---------------- scans ----------------
// y=0: deg_dst -> cur_dst (local exclusive); y=1: deg_src -> cur_src
// y=2: sum_p deg_dst -> mrpl_dst[gid+1] (local inclusive); y=3: same for src
// bsum rows 0..3 = chunk totals; scan2 converts them to exclusive bases.

__global__ void scanA_kernel(const int* __restrict__ deg_dst, const int* __restrict__ deg_src,
                             int* __restrict__ cur_dst, int* __restrict__ cur_src,
                             int* __restrict__ mrpl_dst, int* __restrict__ mrpl_src,
                             int* __restrict__ bsum) {
    __shared__ int sh[SCAN_CHUNK];
    const int y = blockIdx.y;
    const int nelem = (y < 2) ? PN : NNODES;
    if (blockIdx.x * SCAN_CHUNK >= nelem) return;
    int t = threadIdx.x;
    int gid = blockIdx.x * SCAN_CHUNK + t;
    int v = 0;
    if (gid < nelem) {
        if (y == 0) v = deg_dst[gid];
        else if (y == 1) v = deg_src[gid];
        else {
            const int* deg = (y == 2) ? deg_dst : deg_src;
#pragma unroll
            for (int p = 0; p < NPART; p++) v += deg[p * NNODES + gid];
        }
    }
    sh[t] = v;
    __syncthreads();
    for (int off = 1; off < SCAN_CHUNK; off <<= 1) {
        int u = (t >= off) ? sh[t - off] : 0;
        __syncthreads();
        sh[t] += u;
        __syncthreads();
    }
    if (gid < nelem) {
        if (y < 2) ((y == 0) ? cur_dst : cur_src)[gid] = sh[t] - v;
        else ((y == 2) ? mrpl_dst : mrpl_src)[gid + 1] = sh[t];
    }
    if (t == SCAN_CHUNK - 1) bsum[y * 256 + blockIdx.x] = sh[t];
}

__global__ void scan2_kernel(int* __restrict__ bsum) {
    int t = threadIdx.x;
    if (t < 4) {
        int cnt = (t < 2) ? NCHUNK2 : NCHUNKM;
        int run = 0;
        for (int i = 0; i < cnt; i++) {
            int v = bsum[t * 256 + i];
            bsum[t * 256 + i] = run;
            run += v;
        }
    }
}

// ---------------- fill (adds chunk base from bsum inline) ----------------

__global__ void fill_kernel(const int* __restrict__ ei, int* __restrict__ cur_dst,
                            int* __restrict__ cur_src, const int* __restrict__ bsum,
                            unsigned short* __restrict__ col_dst,
                            unsigned short* __restrict__ col_src) {
    int p = blockIdx.x & 7, c = blockIdx.x >> 3;
    int idx = c * 256 + threadIdx.x;
    if (idx >= EPP) return;
    int e = p * EPP + idx;
    int s = ei[e];
    int d = ei[NEDGES + e];
    int i0 = p * NNODES + d;
    int p0 = atomicAdd(&cur_dst[i0], 1) + bsum[i0 >> 10];
    col_dst[p0] = (unsigned short)s;
    int i1 = p * NNODES + s;
    int p1 = atomicAdd(&cur_src[i1], 1) + bsum[256 + (i1 >> 10)];
    col_src[p1] = (unsigned short)d;
}

// ---------------- merge (also finalizes mrp) ----------------
// after fill: cur[i] = local inclusive end; global end = cur[i] + bsum[z*256 + i>>10]
// node start = mrpl[n+1] + bsum[(2+z)*256 + n>>10] - mdeg(n)

__global__ void merge_kernel(const int* __restrict__ deg_dst, const int* __restrict__ deg_src,
                             const int* __restrict__ cur_dst, const int* __restrict__ cur_src,
                             const int* __restrict__ mrpl_dst, const int* __restrict__ mrpl_src,
                             int* __restrict__ mrpf_dst, int* __restrict__ mrpf_src,
                             const int* __restrict__ bsum,
                             const unsigned short* __restrict__ col_dst,
                             const unsigned short* __restrict__ col_src,
                             unsigned short* __restrict__ mcol_dst,
                             unsigned short* __restrict__ mcol_src) {
    const int z = blockIdx.y;
    const int* deg = z ? deg_src : deg_dst;
    const int* cur = z ? cur_src : cur_dst;
    const int* mrpl = z ? mrpl_src : mrpl_dst;
    int* mrpf = z ? mrpf_src : mrpf_dst;
    const unsigned short* col = z ? col_src : col_dst;
    unsigned short* mcol = z ? mcol_src : mcol_dst;
    int n = blockIdx.x * blockDim.x + threadIdx.x;
    if (n >= NNODES) return;
    int dv[NPART];
    int mdeg = 0;
#pragma unroll
    for (int p = 0; p < NPART; p++) {
        dv[p] = deg[p * NNODES + n];
        mdeg += dv[p];
    }
    int start = mrpl[n + 1] + bsum[(2 + z) * 256 + (n >> 10)] - mdeg;
    mrpf[n] = start;
    if (n == NNODES - 1) mrpf[NNODES] = NEDGES;
    int w = start;
#pragma unroll
    for (int p = 0; p < NPART; p++) {
        int i = p * NNODES + n;
        int egl = cur[i] + bsum[z * 256 + (i >> 10)];
        for (int k = egl - dv[p]; k < egl; k++) mcol[w++] = col[k];
    }
}

// ---------------- fp16 MFMA GEMM (BK=32, reg-prefetch, LDS epilogue) ----------------
// y=0: hl_a = xs@Wl[e0];  y=1: hr_a = xt@Wr[e0]
// y=2: hl_b = xt@Wl[e1];  y=3: hr_b = xs@Wr[e1]

__device__ inline half8 ldA8(const _Float16* p) { return *(const half8*)p; }
__device__ inline half8 ldA8(const float* p) {
    float4 a = *(const float4*)p;
    float4 b = *(const float4*)(p + 4);
    half8 r = {(_Float16)a.x, (_Float16)a.y, (_Float16)a.z, (_Float16)a.w,
               (_Float16)b.x, (_Float16)b.y, (_Float16)b.z, (_Float16)b.w};
    return r;
}

#define EPI_STRIDE 264  // halfs

template <typename AT>
__global__ void __launch_bounds__(256)
gemm_f16(const AT* __restrict__ xs, const AT* __restrict__ xt,
         const _Float16* __restrict__ WtL, const _Float16* __restrict__ WtR,
         const float* __restrict__ bl, const float* __restrict__ br,
         _Float16* __restrict__ hbase, int e0) {
    const int y = blockIdx.y;
    const int e = e0 + (y >> 1);
    const AT* A = (y == 0 || y == 3) ? xs : xt;
    const bool left = (y & 1) == 0;
    const _Float16* Wt = (left ? WtL : WtR) + (size_t)e * 65536;
    const float* bvec = (left ? bl : br) + (size_t)e * HC;
    _Float16* C = hbase + (size_t)y * NFE;

    __shared__ __align__(16) _Float16 sh[10240];  // As(2048) | Bs(8192); reused by epilogue
    _Float16* As = sh;
    _Float16* Bs = sh + 2048;

    const int t = threadIdx.x;
    const int lane = t & 63, w = t >> 6;
    const int m0 = blockIdx.x * 64;
    const int rl = lane & 15, ch = lane >> 4;
    const int ar = t >> 2, ac = t & 3;

    floatx4 acc[4][4] = {};

    half8 av = {};
    {
        int gr = m0 + ar;
        if (gr < NNODES) av = ldA8(A + (size_t)gr * 256 + ac * 8);
    }
    half8 bv[4];
#pragma unroll
    for (int j = 0; j < 4; j++)
        bv[j] = *(const half8*)(Wt + (size_t)(ar + j * 64) * 256 + ac * 8);

    for (int k0 = 0; k0 < 256; k0 += 32) {
        __syncthreads();
        *(half8*)(As + ar * 32 + (ac ^ ((ar >> 1) & 3)) * 8) = av;
#pragma unroll
        for (int j = 0; j < 4; j++) {
            int n = ar + j * 64;
            *(half8*)(Bs + n * 32 + (ac ^ ((n >> 1) & 3)) * 8) = bv[j];
        }
        __syncthreads();

        if (k0 + 32 < 256) {
            int gr = m0 + ar;
            if (gr < NNODES) av = ldA8(A + (size_t)gr * 256 + (k0 + 32) + ac * 8);
#pragma unroll
            for (int j = 0; j < 4; j++)
                bv[j] = *(const half8*)(Wt + (size_t)(ar + j * 64) * 256 + (k0 + 32) + ac * 8);
        }

        half8 a[4], b[4];
#pragma unroll
        for (int fm = 0; fm < 4; fm++) {
            int r = fm * 16 + rl;
            a[fm] = *(const half8*)(As + r * 32 + (ch ^ ((r >> 1) & 3)) * 8);
        }
#pragma unroll
        for (int fn = 0; fn < 4; fn++) {
            int n = w * 64 + fn * 16 + rl;
            b[fn] = *(const half8*)(Bs + n * 32 + (ch ^ ((n >> 1) & 3)) * 8);
        }
#pragma unroll
        for (int fm = 0; fm < 4; fm++)
#pragma unroll
            for (int fn = 0; fn < 4; fn++)
                acc[fm][fn] = __builtin_amdgcn_mfma_f32_16x16x32_f16(a[fm], b[fn], acc[fm][fn], 0, 0, 0);
    }

    float bb[4];
#pragma unroll
    for (int fn = 0; fn < 4; fn++) bb[fn] = bvec[w * 64 + fn * 16 + rl];

#pragma unroll
    for (int hh = 0; hh < 2; hh++) {
        __syncthreads();
#pragma unroll
        for (int f2 = 0; f2 < 2; f2++) {
            int fm = hh * 2 + f2;
#pragma unroll
            for (int fn = 0; fn < 4; fn++) {
                int colb = w * 64 + fn * 16 + rl;
#pragma unroll
                for (int j = 0; j < 4; j++) {
                    int lr = f2 * 16 + ch * 4 + j;  // 0..31
                    sh[lr * EPI_STRIDE + colb] = (_Float16)(acc[fm][fn][j] + bb[fn]);
                }
            }
        }
        __syncthreads();
        int lr = t >> 3;            // 0..31
        int cseg = (t & 7) * 32;    // 8 segments x 32 cols (64B)
        int gr = m0 + hh * 32 + lr;
        if (gr < NNODES) {
#pragma unroll
            for (int q = 0; q < 4; q++)
                *(half8*)(C + (size_t)gr * 256 + cseg + q * 8) =
                    *(const half8*)(sh + lr * EPI_STRIDE + cseg + q * 8);
        }
    }
}

// ---------------- fused attention + aggregate (2 edges/wave, 8ch/lane) ----------------

__device__ __forceinline__ void edge_body(half8 hv, half8 hrv, const h2* att2,
                                          float* acc, float& denom, bool valid) {
    const h2 negv = {(_Float16)NEG_SLOPE, (_Float16)NEG_SLOPE};
    const h2* hvp = (const h2*)&hv;
    const h2* hrp = (const h2*)&hrv;
    float v = 0.f;
#pragma unroll
    for (int k = 0; k < 4; k++) {
        h2 x = hvp[k] + hrp[k];
        h2 lk = __builtin_elementwise_max(x, x * negv);
        v = __builtin_amdgcn_fdot2(lk, att2[k], v, false);
    }
    v += __shfl_xor(v, 1);
    v += __shfl_xor(v, 2);
    float pe = __expf(v);
    if (!valid) pe = 0.f;
    denom += pe;
#pragma unroll
    for (int k = 0; k < 8; k++) acc[k] = fmaf((float)hv[k], pe, acc[k]);
}

__device__ inline void store8(float* p, const float* o) {
    floatx4 v0 = {o[0], o[1], o[2], o[3]};
    floatx4 v1 = {o[4], o[5], o[6], o[7]};
    *(floatx4*)p = v0;
    *(floatx4*)(p + 4) = v1;
}
__device__ inline void store8(_Float16* p, const float* o) {
    half8 h = {(_Float16)o[0], (_Float16)o[1], (_Float16)o[2], (_Float16)o[3],
               (_Float16)o[4], (_Float16)o[5], (_Float16)o[6], (_Float16)o[7]};
    *(half8*)p = h;
}

template <typename OT>
__global__ void __launch_bounds__(256)
agg_kernel(const _Float16* __restrict__ hbase,
           const int* __restrict__ mrp_dst, const unsigned short* __restrict__ mcol_dst,
           const int* __restrict__ mrp_src, const unsigned short* __restrict__ mcol_src,
           const float* __restrict__ att, const float* __restrict__ bias,
           OT* __restrict__ out0, OT* __restrict__ out1, int e0, int do_relu) {
    const int z = blockIdx.y;
    const _Float16* hl = hbase + (size_t)z * 2 * NFE;
    const _Float16* hr = hl + NFE;
    const int* mrp = z ? mrp_src : mrp_dst;
    const unsigned short* mcol = z ? mcol_src : mcol_dst;
    const float* attz = att + (size_t)(e0 + z) * HC;
    const float* biasz = bias + (size_t)(e0 + z) * HC;
    OT* out = z ? out1 : out0;

    int wave = threadIdx.x >> 6;
    int lane = threadIdx.x & 63;
    int n = blockIdx.x * 4 + wave;
    if (n >= NNODES) return;
    int h = lane >> 5;       // edge parity within the wave
    int cl = lane & 31;      // channel block (8 channels)
    int c8 = cl << 3;

    const _Float16* hlc = hl + c8;
    half8 hrv = *(const half8*)(hr + (size_t)n * HC + c8);
    float attf[8];
    *(float4*)(attf) = *(const float4*)(attz + c8);
    *(float4*)(attf + 4) = *(const float4*)(attz + c8 + 4);
    h2 att2[4];
#pragma unroll
    for (int k = 0; k < 4; k++) att2[k] = h2{(_Float16)attf[2 * k], (_Float16)attf[2 * k + 1]};

    float acc[8] = {};
    float denom = 0.f;
    int beg = mrp[n], end = mrp[n + 1];

    int i = beg;
    for (; i + 4 <= end; i += 4) {
        int s0 = (int)mcol[i + h];
        int s1 = (int)mcol[i + 2 + h];
        half8 hv0 = *(const half8*)(hlc + ((size_t)s0 << 8));
        half8 hv1 = *(const half8*)(hlc + ((size_t)s1 << 8));
        edge_body(hv0, hrv, att2, acc, denom, true);
        edge_body(hv1, hrv, att2, acc, denom, true);
    }
    for (; i < end; i += 2) {
        int ei = i + h;
        bool valid = ei < end;
        int s0 = (int)mcol[valid ? ei : end - 1];
        half8 hv0 = *(const half8*)(hlc + ((size_t)s0 << 8));
        edge_body(hv0, hrv, att2, acc, denom, valid);
    }

    // merge the two half-wave partials
#pragma unroll
    for (int k = 0; k < 8; k++) acc[k] += __shfl_xor(acc[k], 32);
    denom += __shfl_xor(denom, 32);

    if (lane < 32) {
        float inv = 1.f / (denom + 1e-16f);
        float o[8];
        float b8[8];
        *(float4*)(b8) = *(const float4*)(biasz + c8);
        *(float4*)(b8 + 4) = *(const float4*)(biasz + c8 + 4);
#pragma unroll
        for (int k = 0; k < 8; k++) {
            o[k] = acc[k] * inv + b8[k];
            if (do_relu) o[k] = fmaxf(o[k], 0.f);
        }
        store8(out + (size_t)n * HC + c8, o);
    }
}

// ---------------- launch ----------------

extern "C" void kernel_launch(void* const* d_in, const int* in_sizes, int n_in,
                              void* d_out, int out_size, void* d_ws, size_t ws_size,
                              hipStream_t stream) {
    const float* s = (const float*)d_in[0];
    const float* t = (const float*)d_in[1];
    const float* Wl = (const float*)d_in[2];
    const float* bl = (const float*)d_in[3];
    const float* Wr = (const float*)d_in[4];
    const float* br = (const float*)d_in[5];
    const float* att = (const float*)d_in[6];
    const float* bias = (const float*)d_in[7];
    const int* ei = (const int*)d_in[8];
    float* out = (float*)d_out;

    const size_t NF = (size_t)NFE;

    // workspace layout
    _Float16* os16 = (_Float16*)d_ws;         // NF
    _Float16* ot16 = os16 + NF;               // NF
    _Float16* hbase = ot16 + NF;              // 4*NF
    _Float16* WtL = hbase + 4 * NF;           // 4*65536
    _Float16* WtR = WtL + 4 * 65536;          // 4*65536
    int* deg_dst = (int*)(WtR + 4 * 65536);   // PN
    int* deg_src = deg_dst + PN;              // PN
    int* cur_dst = deg_src + PN;              // PN
    int* cur_src = cur_dst + PN;              // PN
    int* mrpl_dst = cur_src + PN;             // N+1
    int* mrpl_src = mrpl_dst + (NNODES + 1);  // N+1
    int* mrpf_dst = mrpl_src + (NNODES + 1);  // N+1
    int* mrpf_src = mrpf_dst + (NNODES + 1);  // N+1
    int* bsum = mrpf_src + (NNODES + 1);      // 1024
    unsigned short* col_dst = (unsigned short*)(bsum + 1024);  // E
    unsigned short* col_src = col_dst + NEDGES;                // E
    unsigned short* mcol_dst = col_src + NEDGES;               // E
    unsigned short* mcol_src = mcol_dst + NEDGES;              // E

    // ---- CSR build + weight prep ----
    hipMemsetAsync(deg_dst, 0, 2 * PN * sizeof(int), stream);
    prep_kernel<<<512 + NPART * CPP, 256, 0, stream>>>(Wl, Wr, WtL, WtR, ei, deg_dst, deg_src);
    scanA_kernel<<<dim3(NCHUNK2, 4), SCAN_CHUNK, 0, stream>>>(deg_dst, deg_src, cur_dst, cur_src,
                                                              mrpl_dst, mrpl_src, bsum);
    scan2_kernel<<<1, 64, 0, stream>>>(bsum);
    fill_kernel<<<NPART * CPP, 256, 0, stream>>>(ei, cur_dst, cur_src, bsum, col_dst, col_src);
    merge_kernel<<<dim3(118, 2), 256, 0, stream>>>(deg_dst, deg_src, cur_dst, cur_src,
                                                   mrpl_dst, mrpl_src, mrpf_dst, mrpf_src, bsum,
                                                   col_dst, col_src, mcol_dst, mcol_src);

    dim3 ggemm((NNODES + 63) / 64, 4);
    dim3 gagg((NNODES + 3) / 4, 2);

    // layer 0 (fp32 inputs, relu)
    gemm_f16<float><<<ggemm, 256, 0, stream>>>(s, t, WtL, WtR, bl, br, hbase, 0);
    agg_kernel<_Float16><<<gagg, 256, 0, stream>>>(hbase, mrpf_dst, mcol_dst, mrpf_src, mcol_src,
                                                   att, bias, os16, ot16, 0, 1);
    // layer 1 (fp16 inputs, identity, fp32 out)
    gemm_f16<_Float16><<<ggemm, 256, 0, stream>>>(os16, ot16, WtL, WtR, bl, br, hbase, 2);
    agg_kernel<float><<<gagg, 256, 0, stream>>>(hbase, mrpf_dst, mcol_dst, mrpf_src, mcol_src,
                                                att, bias, out, out + NF, 2, 0);
}